// Round 1
// baseline (818.415 us; speedup 1.0000x reference)
//
#include <hip/hip_runtime.h>
#include <hip/hip_bf16.h>

#define E_ 8
#define D_ 1024
#define F_ 4096
#define G_ 2048

typedef __attribute__((ext_vector_type(8))) short bf16x8;
typedef __attribute__((ext_vector_type(4))) float f32x4;
typedef __attribute__((ext_vector_type(8))) unsigned short u16x8;
typedef unsigned short u16;
typedef unsigned int u32;

#define MFMA_ __builtin_amdgcn_mfma_f32_16x16x32_bf16
#define FENCE() asm volatile("" ::: "memory")
#define BAR()                          \
  do {                                 \
    FENCE();                           \
    __builtin_amdgcn_s_barrier();      \
    FENCE();                           \
  } while (0)

// round-to-nearest-even fp32 -> bf16 (branchless)
__device__ __forceinline__ u16 f2bf(float f) {
  u32 u = __float_as_uint(f);
  u = (u + 0x7fffu + ((u >> 16) & 1u)) >> 16;
  return (u16)u;
}

// async global->LDS, 16B per lane; LDS dest = base + lane*16 (wave-uniform base)
__device__ __forceinline__ void gld_lds16(const void* g, void* l) {
  __builtin_amdgcn_global_load_lds(
      (const __attribute__((address_space(1))) u32*)g,
      (__attribute__((address_space(3))) u32*)l, 16, 0, 0);
}

// ---- stage one 128x64 bf16 half-tile (16KB) from global row-major (stride ld)
// into LDS with XOR-8 group swizzle: LDS slot (row, s) holds global 16B-group
// g = s ^ (row&7) of row. LDS dest is LINEAR (gld_lds requirement); the swizzle
// is applied by permuting the per-lane GLOBAL source address (rule #21).
// 512 threads x 2 loads x 16B. Global reads stay within one 128B line per row.
__device__ __forceinline__ void stage_half(const u16* __restrict__ g, int ld,
                                           char* l, int tid) {
  const int wb = (tid & ~63) * 16;  // wave-uniform LDS byte base (lane*16 added by HW)
#pragma unroll
  for (int j = 0; j < 2; j++) {
    const int idx = j * 512 + tid;           // 16B slot index 0..1023
    const int row = idx >> 3;                // 0..127
    const int grp = (idx & 7) ^ (row & 7);   // swizzled global group
    gld_lds16(g + (size_t)row * ld + grp * 8, l + j * 8192 + wb);
  }
}

// fragment read: row r (bf16, 64-elem rows), 16B group gw (0..7 = k-group).
// inverse of the stage swizzle; 16 lanes/quad land 2-way max per bank (free).
__device__ __forceinline__ bf16x8 ld_frag(const u16* base, int r, int gw) {
  return *(const bf16x8*)(base + r * 64 + ((gw ^ (r & 7)) << 3));
}

// ---------------- elementwise fp32 -> bf16 ----------------
__global__ __launch_bounds__(256) void k_cvt(const float* __restrict__ in,
                                             u16* __restrict__ out, int n8) {
  int i = blockIdx.x * 256 + threadIdx.x;
  if (i >= n8) return;
  const float4* p = (const float4*)in + (size_t)i * 2;
  float4 a = p[0], b = p[1];
  u16x8 o;
  o[0] = f2bf(a.x); o[1] = f2bf(a.y); o[2] = f2bf(a.z); o[3] = f2bf(a.w);
  o[4] = f2bf(b.x); o[5] = f2bf(b.y); o[6] = f2bf(b.z); o[7] = f2bf(b.w);
  *(u16x8*)(out + (size_t)i * 8) = o;
}

// ---- transpose+convert: in [B][R][C] fp32 -> out [B][C][R] bf16, 64x64 tiles ----
__global__ __launch_bounds__(256) void k_tcvt(const float* __restrict__ in,
                                              u16* __restrict__ out, int R, int C) {
  __shared__ __align__(16) u16 Tt[64 * 72];
  size_t base = (size_t)blockIdx.z * (size_t)R * (size_t)C;
  in += base; out += base;
  const int c0 = blockIdx.x * 64, r0 = blockIdx.y * 64;
  const int tid = threadIdx.x;
  {
    const int cq = tid & 15, rr = tid >> 4;
    const float* ip = in + (size_t)(r0 + rr) * C + c0 + cq * 4;
#pragma unroll
    for (int i = 0; i < 4; i++) {
      float4 v = *(const float4*)(ip + (size_t)(16 * i) * C);
      const int r = rr + 16 * i, c = cq * 4;
      Tt[(c + 0) * 72 + r] = f2bf(v.x);
      Tt[(c + 1) * 72 + r] = f2bf(v.y);
      Tt[(c + 2) * 72 + r] = f2bf(v.z);
      Tt[(c + 3) * 72 + r] = f2bf(v.w);
    }
  }
  __syncthreads();
  {
    const int rq = tid & 7, cc0 = tid >> 3;
#pragma unroll
    for (int i = 0; i < 2; i++) {
      const int cc = cc0 + 32 * i;
      u16x8 v = *(const u16x8*)(Tt + cc * 72 + rq * 8);
      *(u16x8*)(out + (size_t)(c0 + cc) * R + r0 + rq * 8) = v;
    }
  }
}

// ---------------- fused GEMM1+GEMM2 + SwiGLU: 8-phase-style schedule ----------------
// H = silu(X@W1) * (X@W2) per expert.
// Tile: BM=256 (A), BN=128 per B panel, BK=64. 8 waves as 4m x 2n; each wave owns
// 64x64 of BOTH gemms (acc1/acc2 4x4 f32x4 = 128 VGPR).
// LDS 128KB = 2 bufs x {A0,A1,B1,B2} x 16KB. 4 phases per K-tile, 16 MFMA each,
// raw s_barrier (no vmcnt drain); counted s_waitcnt vmcnt(4) ONCE per K-tile.
// Stage schedule (into buf of tile s while reading tile t, barrier-proven safe):
//   ph1: stage A0(t+1)   [dest buf not read this tile]
//   ph2: stage A1(t+1)
//   ph3: stage B1(t+2)   [B1 region last read at t.ph1]
//   ph4: stage B2(t+2)   [B2 region last read at t.ph3] + vmcnt(4)
__global__ __launch_bounds__(512, 2) void k_mlp1(const u16* __restrict__ X,
                                                 const u16* __restrict__ W1t,
                                                 const u16* __restrict__ W2t,
                                                 u16* __restrict__ H) {
  __shared__ __align__(128) char smem[131072];
  u16* lp = (u16*)smem;
  const int e = blockIdx.z;
  const u16* Ag  = X   + (size_t)e * G_ * D_;
  const u16* B1g = W1t + (size_t)e * F_ * D_;
  const u16* B2g = W2t + (size_t)e * F_ * D_;
  u16* Hp = H + (size_t)e * G_ * F_;
  const int bm = blockIdx.y * 256, bn = blockIdx.x * 128;
  const int tid = threadIdx.x, wave = tid >> 6, lane = tid & 63;
  const int wm = wave >> 1, wn = wave & 1;         // 4m x 2n
  const int quad = lane >> 4, l16 = lane & 15;
  const int NT = D_ / 64;                          // 16 K-tiles

  f32x4 acc1[4][4], acc2[4][4];
#pragma unroll
  for (int i = 0; i < 4; i++)
#pragma unroll
    for (int j = 0; j < 4; j++) {
      acc1[i][j] = f32x4{0.f, 0.f, 0.f, 0.f};
      acc2[i][j] = f32x4{0.f, 0.f, 0.f, 0.f};
    }

  // prologue: A(0) both halves, B1(0), B2(0), B1(1), B2(1)
  stage_half(Ag  + (size_t)bm * D_,              D_, smem,                  tid);
  stage_half(Ag  + (size_t)(bm + 128) * D_,      D_, smem + 16384,          tid);
  stage_half(B1g + (size_t)bn * D_,              D_, smem + 32768,          tid);
  stage_half(B2g + (size_t)bn * D_,              D_, smem + 49152,          tid);
  stage_half(B1g + (size_t)bn * D_ + 64,         D_, smem + 65536 + 32768,  tid);
  stage_half(B2g + (size_t)bn * D_ + 64,         D_, smem + 65536 + 49152,  tid);
  asm volatile("s_waitcnt vmcnt(0)" ::: "memory");
  BAR();

  for (int t = 0; t < NT; ++t) {
    const int q = t & 1, qn = q ^ 1;
    const u16* Aw  = lp + q * 32768 + (wm >> 1) * 8192;  // this wave's A half
    const u16* B1w = lp + q * 32768 + 16384;
    const u16* B2w = lp + q * 32768 + 24576;
    const int ar = (wm & 1) * 64 + l16;  // A row base within half
    const int br = wn * 64 + l16;        // B row base within panel
    bf16x8 afr[4][2], bfr[4][2];

    // ---- phase 1: B1 frags + A m0-1; stage A0(t+1); MFMA gemm1 m0-1 ----
#pragma unroll
    for (int n = 0; n < 4; n++) {
      bfr[n][0] = ld_frag(B1w, br + n * 16, quad);
      bfr[n][1] = ld_frag(B1w, br + n * 16, 4 + quad);
    }
#pragma unroll
    for (int m = 0; m < 2; m++) {
      afr[m][0] = ld_frag(Aw, ar + m * 16, quad);
      afr[m][1] = ld_frag(Aw, ar + m * 16, 4 + quad);
    }
    if (t + 1 < NT)
      stage_half(Ag + (size_t)bm * D_ + (t + 1) * 64, D_, smem + qn * 65536, tid);
    BAR();
    __builtin_amdgcn_s_setprio(1);
#pragma unroll
    for (int m = 0; m < 2; m++)
#pragma unroll
      for (int n = 0; n < 4; n++) {
        acc1[m][n] = MFMA_(afr[m][0], bfr[n][0], acc1[m][n], 0, 0, 0);
        acc1[m][n] = MFMA_(afr[m][1], bfr[n][1], acc1[m][n], 0, 0, 0);
      }
    __builtin_amdgcn_s_setprio(0);
    BAR();

    // ---- phase 2: A m2-3; stage A1(t+1); MFMA gemm1 m2-3 ----
#pragma unroll
    for (int m = 2; m < 4; m++) {
      afr[m][0] = ld_frag(Aw, ar + m * 16, quad);
      afr[m][1] = ld_frag(Aw, ar + m * 16, 4 + quad);
    }
    if (t + 1 < NT)
      stage_half(Ag + (size_t)(bm + 128) * D_ + (t + 1) * 64, D_,
                 smem + qn * 65536 + 16384, tid);
    BAR();
    __builtin_amdgcn_s_setprio(1);
#pragma unroll
    for (int m = 2; m < 4; m++)
#pragma unroll
      for (int n = 0; n < 4; n++) {
        acc1[m][n] = MFMA_(afr[m][0], bfr[n][0], acc1[m][n], 0, 0, 0);
        acc1[m][n] = MFMA_(afr[m][1], bfr[n][1], acc1[m][n], 0, 0, 0);
      }
    __builtin_amdgcn_s_setprio(0);
    BAR();

    // ---- phase 3: B2 frags; stage B1(t+2); MFMA gemm2 m0-1 ----
#pragma unroll
    for (int n = 0; n < 4; n++) {
      bfr[n][0] = ld_frag(B2w, br + n * 16, quad);
      bfr[n][1] = ld_frag(B2w, br + n * 16, 4 + quad);
    }
    if (t + 2 < NT)
      stage_half(B1g + (size_t)bn * D_ + (t + 2) * 64, D_,
                 smem + q * 65536 + 32768, tid);
    BAR();
    __builtin_amdgcn_s_setprio(1);
#pragma unroll
    for (int m = 0; m < 2; m++)
#pragma unroll
      for (int n = 0; n < 4; n++) {
        acc2[m][n] = MFMA_(afr[m][0], bfr[n][0], acc2[m][n], 0, 0, 0);
        acc2[m][n] = MFMA_(afr[m][1], bfr[n][1], acc2[m][n], 0, 0, 0);
      }
    __builtin_amdgcn_s_setprio(0);
    BAR();

    // ---- phase 4: stage B2(t+2); counted vmcnt; MFMA gemm2 m2-3 ----
    if (t + 2 < NT) {
      stage_half(B2g + (size_t)bn * D_ + (t + 2) * 64, D_,
                 smem + q * 65536 + 49152, tid);
      asm volatile("s_waitcnt vmcnt(4)" ::: "memory");
    } else {
      asm volatile("s_waitcnt vmcnt(0)" ::: "memory");
    }
    BAR();
    __builtin_amdgcn_s_setprio(1);
#pragma unroll
    for (int m = 2; m < 4; m++)
#pragma unroll
      for (int n = 0; n < 4; n++) {
        acc2[m][n] = MFMA_(afr[m][0], bfr[n][0], acc2[m][n], 0, 0, 0);
        acc2[m][n] = MFMA_(afr[m][1], bfr[n][1], acc2[m][n], 0, 0, 0);
      }
    __builtin_amdgcn_s_setprio(0);
    BAR();
  }

  // epilogue: SwiGLU, store bf16
#pragma unroll
  for (int m = 0; m < 4; m++)
#pragma unroll
    for (int n = 0; n < 4; n++)
#pragma unroll
      for (int r = 0; r < 4; r++) {
        float mm = acc1[m][n][r], g = acc2[m][n][r];
        float h = (mm / (1.f + __expf(-mm))) * g;
        int row = bm + wm * 64 + m * 16 + quad * 4 + r;
        int col = bn + wn * 64 + n * 16 + l16;
        Hp[(size_t)row * F_ + col] = f2bf(h);
      }
}

// ---------------- GEMM3: out = H @ W3 (256x256 tile, 8-phase-style) ----------------
// 8 waves as 2m x 4n; per-wave 128x64 (acc 8x4). LDS 128KB = 2 bufs x {A0,A1,B0,B1}.
// Phase p reads A m-pair p, 16 MFMA; B frags all read in ph1 and held.
// Stages: ph1 A0(t+1), ph2 A1(t+1), ph3 B0(t+2), ph4 B1(t+2)+vmcnt(4).
__global__ __launch_bounds__(512, 2) void k_mlp2(const u16* __restrict__ H,
                                                 const u16* __restrict__ W3t,
                                                 float* __restrict__ O) {
  __shared__ __align__(128) char smem[131072];
  u16* lp = (u16*)smem;
  const int e = blockIdx.z;
  const u16* Ag = H   + (size_t)e * G_ * F_;
  const u16* Bg = W3t + (size_t)e * D_ * F_;
  float* C = O + (size_t)e * G_ * D_;
  const int bm = blockIdx.y * 256, bn = blockIdx.x * 256;
  const int tid = threadIdx.x, wave = tid >> 6, lane = tid & 63;
  const int wm = wave >> 2, wn = wave & 3;         // 2m x 4n
  const int quad = lane >> 4, l16 = lane & 15;
  const int NT = F_ / 64;                          // 64 K-tiles

  f32x4 acc[8][4];
#pragma unroll
  for (int i = 0; i < 8; i++)
#pragma unroll
    for (int j = 0; j < 4; j++) acc[i][j] = f32x4{0.f, 0.f, 0.f, 0.f};

  // prologue: A(0) halves, B(0) halves, B(1) halves
  stage_half(Ag + (size_t)bm * F_,               F_, smem,                 tid);
  stage_half(Ag + (size_t)(bm + 128) * F_,       F_, smem + 16384,         tid);
  stage_half(Bg + (size_t)bn * F_,               F_, smem + 32768,         tid);
  stage_half(Bg + (size_t)(bn + 128) * F_,       F_, smem + 49152,         tid);
  stage_half(Bg + (size_t)bn * F_ + 64,          F_, smem + 65536 + 32768, tid);
  stage_half(Bg + (size_t)(bn + 128) * F_ + 64,  F_, smem + 65536 + 49152, tid);
  asm volatile("s_waitcnt vmcnt(0)" ::: "memory");
  BAR();

  for (int t = 0; t < NT; ++t) {
    const int q = t & 1, qn = q ^ 1;
    const u16* Aw = lp + q * 32768 + wm * 8192;
    const u16* Bw = lp + q * 32768 + 16384 + (wn >> 1) * 8192;
    const int br = (wn & 1) * 64 + l16;
    bf16x8 bfr[4][2], a0, a1, a2, a3;

    // ---- phase 1: B frags + A m0-1; stage A0(t+1) ----
#pragma unroll
    for (int n = 0; n < 4; n++) {
      bfr[n][0] = ld_frag(Bw, br + n * 16, quad);
      bfr[n][1] = ld_frag(Bw, br + n * 16, 4 + quad);
    }
    a0 = ld_frag(Aw, l16, quad);       a1 = ld_frag(Aw, l16, 4 + quad);
    a2 = ld_frag(Aw, 16 + l16, quad);  a3 = ld_frag(Aw, 16 + l16, 4 + quad);
    if (t + 1 < NT)
      stage_half(Ag + (size_t)bm * F_ + (t + 1) * 64, F_, smem + qn * 65536, tid);
    BAR();
    __builtin_amdgcn_s_setprio(1);
#pragma unroll
    for (int n = 0; n < 4; n++) {
      acc[0][n] = MFMA_(a0, bfr[n][0], acc[0][n], 0, 0, 0);
      acc[0][n] = MFMA_(a1, bfr[n][1], acc[0][n], 0, 0, 0);
      acc[1][n] = MFMA_(a2, bfr[n][0], acc[1][n], 0, 0, 0);
      acc[1][n] = MFMA_(a3, bfr[n][1], acc[1][n], 0, 0, 0);
    }
    __builtin_amdgcn_s_setprio(0);
    BAR();

    // ---- phase 2: A m2-3; stage A1(t+1) ----
    a0 = ld_frag(Aw, 32 + l16, quad);  a1 = ld_frag(Aw, 32 + l16, 4 + quad);
    a2 = ld_frag(Aw, 48 + l16, quad);  a3 = ld_frag(Aw, 48 + l16, 4 + quad);
    if (t + 1 < NT)
      stage_half(Ag + (size_t)(bm + 128) * F_ + (t + 1) * 64, F_,
                 smem + qn * 65536 + 16384, tid);
    BAR();
    __builtin_amdgcn_s_setprio(1);
#pragma unroll
    for (int n = 0; n < 4; n++) {
      acc[2][n] = MFMA_(a0, bfr[n][0], acc[2][n], 0, 0, 0);
      acc[2][n] = MFMA_(a1, bfr[n][1], acc[2][n], 0, 0, 0);
      acc[3][n] = MFMA_(a2, bfr[n][0], acc[3][n], 0, 0, 0);
      acc[3][n] = MFMA_(a3, bfr[n][1], acc[3][n], 0, 0, 0);
    }
    __builtin_amdgcn_s_setprio(0);
    BAR();

    // ---- phase 3: A m4-5; stage B0(t+2) ----
    a0 = ld_frag(Aw, 64 + l16, quad);  a1 = ld_frag(Aw, 64 + l16, 4 + quad);
    a2 = ld_frag(Aw, 80 + l16, quad);  a3 = ld_frag(Aw, 80 + l16, 4 + quad);
    if (t + 2 < NT)
      stage_half(Bg + (size_t)bn * F_ + (t + 2) * 64, F_,
                 smem + q * 65536 + 32768, tid);
    BAR();
    __builtin_amdgcn_s_setprio(1);
#pragma unroll
    for (int n = 0; n < 4; n++) {
      acc[4][n] = MFMA_(a0, bfr[n][0], acc[4][n], 0, 0, 0);
      acc[4][n] = MFMA_(a1, bfr[n][1], acc[4][n], 0, 0, 0);
      acc[5][n] = MFMA_(a2, bfr[n][0], acc[5][n], 0, 0, 0);
      acc[5][n] = MFMA_(a3, bfr[n][1], acc[5][n], 0, 0, 0);
    }
    __builtin_amdgcn_s_setprio(0);
    BAR();

    // ---- phase 4: A m6-7; stage B1(t+2); counted vmcnt ----
    a0 = ld_frag(Aw, 96 + l16, quad);   a1 = ld_frag(Aw, 96 + l16, 4 + quad);
    a2 = ld_frag(Aw, 112 + l16, quad);  a3 = ld_frag(Aw, 112 + l16, 4 + quad);
    if (t + 2 < NT) {
      stage_half(Bg + (size_t)(bn + 128) * F_ + (t + 2) * 64, F_,
                 smem + q * 65536 + 49152, tid);
      asm volatile("s_waitcnt vmcnt(4)" ::: "memory");
    } else {
      asm volatile("s_waitcnt vmcnt(0)" ::: "memory");
    }
    BAR();
    __builtin_amdgcn_s_setprio(1);
#pragma unroll
    for (int n = 0; n < 4; n++) {
      acc[6][n] = MFMA_(a0, bfr[n][0], acc[6][n], 0, 0, 0);
      acc[6][n] = MFMA_(a1, bfr[n][1], acc[6][n], 0, 0, 0);
      acc[7][n] = MFMA_(a2, bfr[n][0], acc[7][n], 0, 0, 0);
      acc[7][n] = MFMA_(a3, bfr[n][1], acc[7][n], 0, 0, 0);
    }
    __builtin_amdgcn_s_setprio(0);
    BAR();
  }

#pragma unroll
  for (int m = 0; m < 8; m++)
#pragma unroll
    for (int n = 0; n < 4; n++)
#pragma unroll
      for (int r = 0; r < 4; r++) {
        int row = bm + wm * 128 + m * 16 + quad * 4 + r;
        int col = bn + wn * 64 + n * 16 + l16;
        C[(size_t)row * D_ + col] = acc[m][n][r];
      }
}

extern "C" void kernel_launch(void* const* d_in, const int* in_sizes, int n_in,
                              void* d_out, int out_size, void* d_ws, size_t ws_size,
                              hipStream_t stream) {
  const float* x  = (const float*)d_in[0];  // [E*G, D]
  const float* w1 = (const float*)d_in[1];  // [E*D, F]
  const float* w2 = (const float*)d_in[2];  // [E*D, F]
  const float* w3 = (const float*)d_in[3];  // [E*F, D]
  float* out = (float*)d_out;               // [E*G, D] fp32
  char* ws = (char*)d_ws;

  // workspace layout (288MB total):
  //   Xb  [0,   32MB)  bf16 [E][G][D]     (dead after k_mlp1)
  //   W1t [32,  96MB)  bf16 [E][F][D]     (dead after k_mlp1)
  //   W2t [96, 160MB)  bf16 [E][F][D]     (dead after k_mlp1)
  //   Hb  [160,288MB)  bf16 [E][G][F]
  //   W3t [0,   64MB)  bf16 [E][D][F]     (written AFTER k_mlp1; aliases Xb/W1t-head)
  u16* Xb  = (u16*)(ws);
  u16* W1t = (u16*)(ws + (size_t)32 * 1024 * 1024);
  u16* W2t = (u16*)(ws + (size_t)96 * 1024 * 1024);
  u16* Hb  = (u16*)(ws + (size_t)160 * 1024 * 1024);
  u16* W3t = (u16*)(ws);

  // 1) X fp32->bf16
  k_cvt<<<dim3((E_ * G_ * D_ / 8 + 255) / 256), dim3(256), 0, stream>>>(
      x, Xb, E_ * G_ * D_ / 8);
  // 2) W1,W2: [D,F] -> [F,D] bf16
  k_tcvt<<<dim3(F_ / 64, D_ / 64, E_), dim3(256), 0, stream>>>(w1, W1t, D_, F_);
  k_tcvt<<<dim3(F_ / 64, D_ / 64, E_), dim3(256), 0, stream>>>(w2, W2t, D_, F_);
  // 3) hidden = silu(X@W1) * (X@W2)   [256x128x2 tile, 8-phase schedule]
  k_mlp1<<<dim3(F_ / 128, G_ / 256, E_), dim3(512), 0, stream>>>(Xb, W1t, W2t, Hb);
  // 4) W3: [F,D] -> [D,F] bf16 (into region freed by Xb/W1t)
  k_tcvt<<<dim3(D_ / 64, F_ / 64, E_), dim3(256), 0, stream>>>(w3, W3t, F_, D_);
  // 5) out = hidden @ W3   [256x256 tile, 8-phase schedule]
  k_mlp2<<<dim3(D_ / 256, G_ / 256, E_), dim3(512), 0, stream>>>(Hb, W3t, out);
}